// Round 7
// baseline (402.815 us; speedup 1.0000x reference)
//
#include <hip/hip_runtime.h>
#include <hip/hip_bf16.h>

#define B_ 16384
#define NF_ 16
#define VOCAB_ 100000
#define ED_ 32
#define NNUM_ 13
#define E_ 8
#define T_ 2
#define H0_ 512
#define H1_ 256
#define TH_ 128
#define D0_ 525
#define K0P 576   // padded K for layer 0 (multiple of 64; odd tile count handled by tail)

typedef __bf16 bf16x8 __attribute__((ext_vector_type(8)));
typedef float  f32x4  __attribute__((ext_vector_type(4)));

typedef __attribute__((address_space(3))) void lds_void;
typedef __attribute__((address_space(1))) const void gbl_void;

__device__ __forceinline__ void load_lds16f(const void* g, void* l) {
  __builtin_amdgcn_global_load_lds((gbl_void*)g, (lds_void*)l, 16, 0, 0);
}

#define BARX                                        \
  do {                                              \
    asm volatile("" ::: "memory");                  \
    __builtin_amdgcn_s_barrier();                   \
    __builtin_amdgcn_sched_barrier(0);              \
    asm volatile("" ::: "memory");                  \
  } while (0)
#define LGKM0                                       \
  do {                                              \
    asm volatile("s_waitcnt lgkmcnt(0)" ::: "memory"); \
    __builtin_amdgcn_sched_barrier(0);              \
  } while (0)

// ---------------- embedding + concat + pad + cast ----------------
__global__ __launch_bounds__(256) void k_embed(const int* __restrict__ cat,
                                               const float* __restrict__ num,
                                               const float* __restrict__ emb,
                                               __hip_bfloat16* __restrict__ x) {
  int b = blockIdx.x;
  int t = threadIdx.x;
  const int* crow = cat + b * NF_;
#pragma unroll
  for (int i = 0; i < 3; ++i) {
    int d = t + i * 256;  // 0..767
    if (d >= K0P) continue;
    float v;
    if (d < 512) {
      int f = d >> 5, c = d & 31;
      v = emb[((long long)(f * VOCAB_ + crow[f])) * ED_ + c];
    } else if (d < D0_) {
      v = num[b * NNUM_ + (d - 512)];
    } else {
      v = 0.f;
    }
    x[(long long)b * K0P + d] = __float2bfloat16(v);
  }
}

// ---------------- weight transpose + pad + cast: W[E][K][N] f32 -> Wp[E][N][KP] bf16 ----------------
__global__ __launch_bounds__(256) void k_wprep(const float* __restrict__ W,
                                               __hip_bfloat16* __restrict__ Wp,
                                               int K, int N, int KP) {
  __shared__ float tile[64][65];
  int k0 = blockIdx.x * 64, n0 = blockIdx.y * 64, e = blockIdx.z;
  int tx = threadIdx.x & 63, ty = threadIdx.x >> 6;
  for (int r = ty; r < 64; r += 4) {
    int k = k0 + r;
    tile[r][tx] = (k < K) ? W[((long long)e * K + k) * N + n0 + tx] : 0.f;
  }
  __syncthreads();
  for (int r = ty; r < 64; r += 4) {
    int n = n0 + r;
    Wp[((long long)e * N + n) * KP + k0 + tx] = __float2bfloat16(tile[tx][r]);
  }
}

// ---------------- BN param folding ----------------
__global__ void k_prep_small(const float* b0, const float* g0, const float* be0,
                             const float* m0, const float* v0,
                             const float* b1, const float* g1, const float* be1,
                             const float* m1, const float* v1,
                             const float* bt1, const float* tg, const float* tb,
                             const float* tm, const float* tv,
                             float* scale0, float* ebias0, float* scale1, float* ebias1,
                             float* tscale, float* tbias) {
  int i = blockIdx.x * 256 + threadIdx.x;
  if (i < H0_) scale0[i] = g0[i] * rsqrtf(v0[i] + 1e-5f);
  if (i < H1_) scale1[i] = g1[i] * rsqrtf(v1[i] + 1e-5f);
  if (i < T_ * TH_) {
    float s = tg[i] * rsqrtf(tv[i] + 1e-5f);
    tscale[i] = s;
    tbias[i] = (bt1[i] - tm[i]) * s + tb[i];
  }
  if (i < E_ * H0_) {
    int n = i & (H0_ - 1);
    float s = g0[n] * rsqrtf(v0[n] + 1e-5f);
    ebias0[i] = (b0[i] - m0[n]) * s + be0[n];
  }
  if (i < E_ * H1_) {
    int n = i & (H1_ - 1);
    float s = g1[n] * rsqrtf(v1[n] + 1e-5f);
    ebias1[i] = (b1[i] - m1[n]) * s + be1[n];
  }
}

// ---------------- gate logits + softmax over 8 experts ----------------
__global__ __launch_bounds__(256) void k_gates(const __hip_bfloat16* __restrict__ x,
                                               const float* __restrict__ Wg,
                                               const float* __restrict__ bg,
                                               float* __restrict__ gates) {
  int gidx = blockIdx.x * 256 + threadIdx.x;
  int b = gidx >> 4, te = gidx & 15;
  int t = te >> 3, e = te & 7;
  const __hip_bfloat16* xr = x + (long long)b * K0P;
  const float* wg = Wg + ((long long)t * D0_) * E_ + e;
  float acc = bg[t * E_ + e];
  int k = 0;
  for (; k + 8 <= D0_; k += 8) {
    bf16x8 xv = *reinterpret_cast<const bf16x8*>(xr + k);
#pragma unroll
    for (int j = 0; j < 8; ++j)
      acc += (float)xv[j] * wg[(long long)(k + j) * E_];
  }
  for (; k < D0_; ++k) acc += __bfloat162float(xr[k]) * wg[(long long)k * E_];
  float mx = acc;
#pragma unroll
  for (int o = 1; o < 8; o <<= 1) mx = fmaxf(mx, __shfl_xor(mx, o));
  float p = __expf(acc - mx);
  float s = p;
#pragma unroll
  for (int o = 1; o < 8; o <<= 1) s += __shfl_xor(s, o);
  gates[((long long)t * B_ + b) * E_ + e] = p / s;
}

// ---------------- grouped GEMM + BN + ReLU -> bf16, 8-phase schedule ----------------
// 256x256 tile, BK=64, 8 waves; odd K-tile count handled by drained tail.
// Epilogue: acc -> LDS (chunk-swizzled) -> coalesced dwordx4 C stores.
__global__ __launch_bounds__(512, 2) void k_gemm(
    const __hip_bfloat16* __restrict__ Aall, long long strideAe, int lda,
    const __hip_bfloat16* __restrict__ Ball, long long strideBe, int ldb,
    __hip_bfloat16* __restrict__ Call, long long strideCe, int N,
    const float* __restrict__ scale, const float* __restrict__ ebias, int strideEb,
    int K) {
  __shared__ __align__(16) char SMEM[131072];
  char (*As)[2][16384] = reinterpret_cast<char (*)[2][16384]>(SMEM);           // [slot][half]
  char (*Bs)[2][16384] = reinterpret_cast<char (*)[2][16384]>(SMEM + 65536);

  const int e = blockIdx.z;
  const char* A = reinterpret_cast<const char*>(Aall + (long long)e * strideAe +
                                                (long long)blockIdx.x * 256 * lda);
  const char* Bw = reinterpret_cast<const char*>(Ball + (long long)e * strideBe +
                                                 (long long)blockIdx.y * 256 * ldb);
  const int ldab = lda * 2, ldbb = ldb * 2;

  const int tid = threadIdx.x;
  const int lane = tid & 63;
  const int wid = tid >> 6;
  const int wq_r = wid >> 2, wq_c = wid & 3;  // within-quadrant: 2Mx4N waves

  const int srow = tid >> 3;                          // 0..63
  const int swz = ((tid & 7) << 4) ^ ((srow & 7) << 4);

  auto STG_A = [&](int kt, int half, int slot) {
#pragma unroll
    for (int j = 0; j < 2; ++j) {
      const int lrow = srow + j * 64;
      load_lds16f(A + (long long)(half * 128 + lrow) * ldab + kt * 128 + swz,
                  &As[slot][half][j * 8192 + tid * 16]);
    }
  };
  auto STG_B = [&](int kt, int half, int slot) {
#pragma unroll
    for (int j = 0; j < 2; ++j) {
      const int lrow = srow + j * 64;
      load_lds16f(Bw + (long long)(half * 128 + lrow) * ldbb + kt * 128 + swz,
                  &Bs[slot][half][j * 8192 + tid * 16]);
    }
  };

  bf16x8 af[2][4], bq[2][2];
  auto LDA = [&](int slot, int half) {
#pragma unroll
    for (int kk = 0; kk < 2; ++kk) {
      const int kb = kk * 64 + (lane >> 4) * 16;
#pragma unroll
      for (int m = 0; m < 4; ++m) {
        const int lrow = wq_r * 64 + m * 16 + (lane & 15);
        af[kk][m] = *reinterpret_cast<const bf16x8*>(
            &As[slot][half][lrow * 128 + (kb ^ ((lane & 7) << 4))]);
      }
    }
  };
  auto LDB = [&](int slot, int half) {
#pragma unroll
    for (int kk = 0; kk < 2; ++kk) {
      const int kb = kk * 64 + (lane >> 4) * 16;
#pragma unroll
      for (int n = 0; n < 2; ++n) {
        const int lrow = wq_c * 32 + n * 16 + (lane & 15);
        bq[kk][n] = *reinterpret_cast<const bf16x8*>(
            &Bs[slot][half][lrow * 128 + (kb ^ ((lane & 7) << 4))]);
      }
    }
  };

  f32x4 acc[2][2][4][2];
#pragma unroll
  for (int a = 0; a < 2; ++a)
#pragma unroll
    for (int b = 0; b < 2; ++b)
#pragma unroll
      for (int m = 0; m < 4; ++m)
#pragma unroll
        for (int n = 0; n < 2; ++n) acc[a][b][m][n] = (f32x4){0.f, 0.f, 0.f, 0.f};

#define MMQ(QM, QN)                                                            \
  do {                                                                         \
    __builtin_amdgcn_s_setprio(1);                                             \
    _Pragma("unroll") for (int kk = 0; kk < 2; ++kk)                           \
        _Pragma("unroll") for (int m = 0; m < 4; ++m)                          \
            _Pragma("unroll") for (int n = 0; n < 2; ++n)                      \
                acc[QM][QN][m][n] = __builtin_amdgcn_mfma_f32_16x16x32_bf16(   \
                    af[kk][m], bq[kk][n], acc[QM][QN][m][n], 0, 0, 0);         \
    __builtin_amdgcn_s_setprio(0);                                             \
  } while (0)

  const int nk = K / 64;
  const int nj = nk >> 1;  // pairs; odd nk -> tail tile nk-1 (even index, slot 0)

  // prologue: t0 full, then t1.A0, t1.B1 -> vmcnt(4): t0 landed
  STG_A(0, 0, 0); STG_A(0, 1, 0); STG_B(0, 0, 0); STG_B(0, 1, 0);
  if (nk > 1) { STG_A(1, 0, 1); STG_B(1, 1, 1); }
  asm volatile("s_waitcnt vmcnt(4)" ::: "memory");
  BARX;

  for (int j = 0; j < nj; ++j) {
    const int t1 = 2 * j + 1, t2 = 2 * j + 2, t3 = 2 * j + 3;
    const bool more = (t2 < nk);
    const bool more3 = (t3 < nk);
    // ---- tile t0 = 2j (slot 0) ----
    LDA(0, 0); LDB(0, 0);
    STG_A(t1, 1, 1);
    BARX; LGKM0; MMQ(0, 0); BARX;
    LDB(0, 1);
    STG_B(t1, 0, 1);
    BARX; LGKM0; MMQ(0, 1); BARX;
    LDA(0, 1);
    if (more) STG_A(t2, 0, 0);
    BARX; LGKM0; MMQ(1, 1); BARX;
    LDB(0, 0);
    if (more) STG_B(t2, 1, 0);
    BARX; LGKM0; MMQ(1, 0);
    if (more) { asm volatile("s_waitcnt vmcnt(4)" ::: "memory"); }
    else      { asm volatile("s_waitcnt vmcnt(0)" ::: "memory"); }
    BARX;
    // ---- tile t1 (slot 1) ----
    LDA(1, 0); LDB(1, 0);
    if (more) STG_A(t2, 1, 0);
    BARX; LGKM0; MMQ(0, 0); BARX;
    LDB(1, 1);
    if (more) STG_B(t2, 0, 0);
    BARX; LGKM0; MMQ(0, 1); BARX;
    LDA(1, 1);
    if (more3) STG_A(t3, 0, 1);
    BARX; LGKM0; MMQ(1, 1); BARX;
    LDB(1, 0);
    if (more3) STG_B(t3, 1, 1);
    BARX; LGKM0; MMQ(1, 0);
    if (more) { asm volatile("s_waitcnt vmcnt(4)" ::: "memory"); }
    BARX;
  }

  if (nk & 1) {
    // tail tile nk-1 staged into slot 0 during the last pair (phases 3-6)
    asm volatile("s_waitcnt vmcnt(0)" ::: "memory");
    BARX;
    LDA(0, 0); LDB(0, 0); LGKM0; MMQ(0, 0);
    LDB(0, 1);            LGKM0; MMQ(0, 1);
    LDA(0, 1);            LGKM0; MMQ(1, 1);
    LDB(0, 0);            LGKM0; MMQ(1, 0);
  }
#undef MMQ

  // ---- epilogue: acc -> LDS (chunk-swizzled) -> coalesced dwordx4 stores ----
  __syncthreads();  // all MFMA reads of SMEM done (covers barrier-free tail)
  __hip_bfloat16* C = Call + (long long)e * strideCe;
  const float* eb = ebias + e * strideEb;
  const int m0 = blockIdx.x * 256, n0 = blockIdx.y * 256;
#pragma unroll
  for (int Qm = 0; Qm < 2; ++Qm)
#pragma unroll
    for (int Qn = 0; Qn < 2; ++Qn)
#pragma unroll
      for (int n = 0; n < 2; ++n) {
        const int col = Qn * 128 + wq_c * 32 + n * 16 + (lane & 15);
        const float s = scale[n0 + col];
        const float bb = eb[n0 + col];
#pragma unroll
        for (int m = 0; m < 4; ++m) {
#pragma unroll
          for (int i = 0; i < 4; ++i) {
            const int row = Qm * 128 + wq_r * 64 + m * 16 + (lane >> 4) * 4 + i;
            const float v = fmaxf(acc[Qm][Qn][m][n][i] * s + bb, 0.f);
            const int byt = row * 512 + ((((col >> 3) ^ (row & 7)) << 4) | ((col & 7) << 1));
            *reinterpret_cast<__hip_bfloat16*>(SMEM + byt) = __float2bfloat16(v);
          }
        }
      }
  __syncthreads();
#pragma unroll
  for (int it = 0; it < 16; ++it) {
    const int row = it * 16 + (tid >> 5);
    const int c16 = tid & 31;
    const f32x4 d = *reinterpret_cast<const f32x4*>(
        SMEM + row * 512 + ((c16 ^ (row & 7)) << 4));
    *reinterpret_cast<f32x4*>(
        reinterpret_cast<char*>(C + (long long)(m0 + row) * N + n0) + c16 * 16) = d;
  }
}

// ---------------- gate-weighted combine: fea[t][b][:] = sum_e g[t][b][e]*h1[e][b][:] ----------------
__global__ __launch_bounds__(256) void k_combine(const __hip_bfloat16* __restrict__ h1,
                                                 const float* __restrict__ gates,
                                                 __hip_bfloat16* __restrict__ fea) {
  const int idx = blockIdx.x * 256 + threadIdx.x;  // 0 .. B*H1/8-1
  const int b = idx >> 5, c = idx & 31;
  const f32x4* gp0 = reinterpret_cast<const f32x4*>(gates + (long long)b * E_);
  const f32x4* gp1 = reinterpret_cast<const f32x4*>(gates + ((long long)B_ + b) * E_);
  const f32x4 g0lo = gp0[0], g0hi = gp0[1];
  const f32x4 g1lo = gp1[0], g1hi = gp1[1];

  float a0[8], a1[8];
#pragma unroll
  for (int j = 0; j < 8; ++j) { a0[j] = 0.f; a1[j] = 0.f; }

#pragma unroll
  for (int ee = 0; ee < 8; ++ee) {
    bf16x8 hv = *reinterpret_cast<const bf16x8*>(
        h1 + ((long long)ee * B_ + b) * H1_ + c * 8);
    const float ga = (ee < 4) ? g0lo[ee & 3] : g0hi[ee & 3];
    const float gb = (ee < 4) ? g1lo[ee & 3] : g1hi[ee & 3];
#pragma unroll
    for (int j = 0; j < 8; ++j) {
      float v = (float)hv[j];
      a0[j] += ga * v;
      a1[j] += gb * v;
    }
  }
  bf16x8 o0, o1;
#pragma unroll
  for (int j = 0; j < 8; ++j) { o0[j] = (__bf16)a0[j]; o1[j] = (__bf16)a1[j]; }
  *reinterpret_cast<bf16x8*>(fea + (long long)b * H1_ + c * 8) = o0;
  *reinterpret_cast<bf16x8*>(fea + ((long long)B_ + b) * H1_ + c * 8) = o1;
}

// ---------------- per-task tower MLP + sigmoid ----------------
__global__ __launch_bounds__(256) void k_tower2(
    const __hip_bfloat16* __restrict__ fea, const float* __restrict__ Wt1,
    const float* __restrict__ Wt2, const float* __restrict__ bt2,
    const float* __restrict__ tscale, const float* __restrict__ tbias,
    float* __restrict__ out) {
  __shared__ __align__(16) char Ws[TH_ * 512];  // Ws[h][k] bf16, swizzled
  const int t = blockIdx.y;
  const int tid = threadIdx.x;
  const int lane = tid & 63, wv = tid >> 6;

  const int row = blockIdx.x * 64 + wv * 16 + (lane & 15);
  const int g4 = lane >> 4;

  for (int it = 0; it < 16; ++it) {
    int idx = it * 256 + tid;
    int h = idx & 127, kc = idx >> 7;
    bf16x8 v;
#pragma unroll
    for (int j = 0; j < 8; ++j)
      v[j] = (__bf16)Wt1[((long long)t * H1_ + kc * 8 + j) * TH_ + h];
    int byt = h * 512 + ((kc * 16) ^ ((h & 7) << 4));
    *reinterpret_cast<bf16x8*>(Ws + byt) = v;
  }

  bf16x8 af[8];
  {
    const __hip_bfloat16* fp = fea + ((long long)t * B_ + row) * H1_ + g4 * 8;
#pragma unroll
    for (int c = 0; c < 8; ++c)
      af[c] = *reinterpret_cast<const bf16x8*>(fp + c * 32);
  }
  __syncthreads();

  f32x4 acc[8];
#pragma unroll
  for (int n = 0; n < 8; ++n) acc[n] = (f32x4){0.f, 0.f, 0.f, 0.f};
#pragma unroll
  for (int c = 0; c < 8; ++c) {
    int kb = c * 64 + g4 * 16;
#pragma unroll
    for (int n = 0; n < 8; ++n) {
      int hrow = n * 16 + (lane & 15);
      bf16x8 bv = *reinterpret_cast<const bf16x8*>(Ws + hrow * 512 + (kb ^ ((hrow & 7) << 4)));
      acc[n] = __builtin_amdgcn_mfma_f32_16x16x32_bf16(af[c], bv, acc[n], 0, 0, 0);
    }
  }

  float part[4] = {0.f, 0.f, 0.f, 0.f};
#pragma unroll
  for (int n = 0; n < 8; ++n) {
    int col = n * 16 + (lane & 15);
    float s = tscale[t * TH_ + col], bb = tbias[t * TH_ + col], w2 = Wt2[t * TH_ + col];
#pragma unroll
    for (int i = 0; i < 4; ++i)
      part[i] += fmaxf(acc[n][i] * s + bb, 0.f) * w2;
  }
#pragma unroll
  for (int o = 1; o < 16; o <<= 1) {
#pragma unroll
    for (int i = 0; i < 4; ++i) part[i] += __shfl_xor(part[i], o);
  }
  if ((lane & 15) == 0) {
    int rbase = blockIdx.x * 64 + wv * 16 + g4 * 4;
    float b2 = bt2[t];
#pragma unroll
    for (int i = 0; i < 4; ++i) {
      float z = part[i] + b2;
      out[(long long)t * B_ + rbase + i] = 1.f / (1.f + __expf(-z));
    }
  }
}

extern "C" void kernel_launch(void* const* d_in, const int* in_sizes, int n_in,
                              void* d_out, int out_size, void* d_ws, size_t ws_size,
                              hipStream_t stream) {
  const int*   cat = (const int*)d_in[0];
  const float* num = (const float*)d_in[1];
  const float* emb = (const float*)d_in[3];
  const float* W0  = (const float*)d_in[4];
  const float* b0  = (const float*)d_in[5];
  const float* g0  = (const float*)d_in[6];
  const float* be0 = (const float*)d_in[7];
  const float* m0  = (const float*)d_in[8];
  const float* v0  = (const float*)d_in[9];
  const float* W1  = (const float*)d_in[10];
  const float* b1  = (const float*)d_in[11];
  const float* g1  = (const float*)d_in[12];
  const float* be1 = (const float*)d_in[13];
  const float* m1  = (const float*)d_in[14];
  const float* v1  = (const float*)d_in[15];
  const float* Wg  = (const float*)d_in[16];
  const float* bg  = (const float*)d_in[17];
  const float* Wt1 = (const float*)d_in[18];
  const float* bt1 = (const float*)d_in[19];
  const float* tg  = (const float*)d_in[20];
  const float* tb  = (const float*)d_in[21];
  const float* tm  = (const float*)d_in[22];
  const float* tv  = (const float*)d_in[23];
  const float* Wt2 = (const float*)d_in[24];
  const float* bt2 = (const float*)d_in[25];
  float* out = (float*)d_out;

  char* ws = (char*)d_ws;
  if (ws_size < 247496704ULL) return;

  __hip_bfloat16* x_bf = (__hip_bfloat16*)(ws + 0ULL);            // 16384*576*2
  __hip_bfloat16* W0p  = (__hip_bfloat16*)(ws + 20971520ULL);     // 8*512*576*2
  __hip_bfloat16* W1p  = (__hip_bfloat16*)(ws + 26214400ULL);     // 8*256*512*2
  float* gates   = (float*)(ws + 28311552ULL);                    // 2*16384*8*4
  float* scale0  = (float*)(ws + 29360128ULL);
  float* ebias0  = (float*)(ws + 29362176ULL);
  float* scale1  = (float*)(ws + 29378560ULL);
  float* ebias1  = (float*)(ws + 29379584ULL);
  float* tscale  = (float*)(ws + 29387776ULL);
  float* tbias   = (float*)(ws + 29388800ULL);
  __hip_bfloat16* h0  = (__hip_bfloat16*)(ws + 29392896ULL);      // 8*16384*512*2
  __hip_bfloat16* h1  = (__hip_bfloat16*)(ws + 163610624ULL);     // 8*16384*256*2
  __hip_bfloat16* fea = (__hip_bfloat16*)(ws + 230719488ULL);     // 2*16384*256*2

  // weight prep + BN folding
  k_wprep<<<dim3(K0P / 64, H0_ / 64, E_), 256, 0, stream>>>(W0, W0p, D0_, H0_, K0P);
  k_wprep<<<dim3(H0_ / 64, H1_ / 64, E_), 256, 0, stream>>>(W1, W1p, H0_, H1_, H0_);
  k_prep_small<<<16, 256, 0, stream>>>(b0, g0, be0, m0, v0, b1, g1, be1, m1, v1,
                                       bt1, tg, tb, tm, tv,
                                       scale0, ebias0, scale1, ebias1, tscale, tbias);
  // embedding + concat
  k_embed<<<B_, 256, 0, stream>>>(cat, num, emb, x_bf);
  // gates
  k_gates<<<B_ * 16 / 256, 256, 0, stream>>>(x_bf, Wg, bg, gates);
  // layer 0: [B,576] x [E,512,576]^T -> h0 [E,B,512]  (nk=9, odd tail)
  k_gemm<<<dim3(B_ / 256, H0_ / 256, E_), 512, 0, stream>>>(
      x_bf, 0LL, K0P, W0p, (long long)H0_ * K0P, K0P,
      h0, (long long)B_ * H0_, H0_, scale0, ebias0, H0_, K0P);
  // layer 1: h0 [E,B,512] x [E,256,512]^T -> h1 [E,B,256]  (nk=8, even)
  k_gemm<<<dim3(B_ / 256, H1_ / 256, E_), 512, 0, stream>>>(
      h0, (long long)B_ * H0_, H0_, W1p, (long long)H1_ * H0_, H0_,
      h1, (long long)B_ * H1_, H1_, scale1, ebias1, H1_, H0_);
  // gate-weighted combine (both tasks, one h1 pass)
  k_combine<<<B_ * H1_ / 8 / 256, 256, 0, stream>>>(h1, gates, fea);
  // per-task tower MLP + sigmoid
  k_tower2<<<dim3(B_ / 64, T_), 256, 0, stream>>>(fea, Wt1, Wt2, bt2,
                                                  tscale, tbias, out);
}

// Round 8
// 258.929 us; speedup vs baseline: 1.5557x; 1.5557x over previous
//
#include <hip/hip_runtime.h>
#include <hip/hip_bf16.h>

#define B_ 16384
#define NF_ 16
#define VOCAB_ 100000
#define ED_ 32
#define NNUM_ 13
#define E_ 8
#define T_ 2
#define H0_ 512
#define H1_ 256
#define TH_ 128
#define D0_ 525
#define K0P 640   // padded K for layer 0 (multiple of 128 -> even # of 64-K-tiles, no tail)

typedef __bf16 bf16x8 __attribute__((ext_vector_type(8)));
typedef float  f32x4  __attribute__((ext_vector_type(4)));

typedef __attribute__((address_space(3))) void lds_void;
typedef __attribute__((address_space(1))) const void gbl_void;

__device__ __forceinline__ void load_lds16f(const void* g, void* l) {
  __builtin_amdgcn_global_load_lds((gbl_void*)g, (lds_void*)l, 16, 0, 0);
}

#define BARX                                        \
  do {                                              \
    asm volatile("" ::: "memory");                  \
    __builtin_amdgcn_s_barrier();                   \
    __builtin_amdgcn_sched_barrier(0);              \
    asm volatile("" ::: "memory");                  \
  } while (0)
#define LGKM0                                       \
  do {                                              \
    asm volatile("s_waitcnt lgkmcnt(0)" ::: "memory"); \
    __builtin_amdgcn_sched_barrier(0);              \
  } while (0)

// ---------------- embedding + concat + pad + cast ----------------
__global__ __launch_bounds__(256) void k_embed(const int* __restrict__ cat,
                                               const float* __restrict__ num,
                                               const float* __restrict__ emb,
                                               __hip_bfloat16* __restrict__ x) {
  int b = blockIdx.x;
  int t = threadIdx.x;
  const int* crow = cat + b * NF_;
#pragma unroll
  for (int i = 0; i < 3; ++i) {
    int d = t + i * 256;  // 0..767
    if (d >= K0P) continue;
    float v;
    if (d < 512) {
      int f = d >> 5, c = d & 31;
      v = emb[((long long)(f * VOCAB_ + crow[f])) * ED_ + c];
    } else if (d < D0_) {
      v = num[b * NNUM_ + (d - 512)];
    } else {
      v = 0.f;
    }
    x[(long long)b * K0P + d] = __float2bfloat16(v);
  }
}

// ---------------- weight transpose + pad + cast: W[E][K][N] f32 -> Wp[E][N][KP] bf16 ----------------
__global__ __launch_bounds__(256) void k_wprep(const float* __restrict__ W,
                                               __hip_bfloat16* __restrict__ Wp,
                                               int K, int N, int KP) {
  __shared__ float tile[64][65];
  int k0 = blockIdx.x * 64, n0 = blockIdx.y * 64, e = blockIdx.z;
  int tx = threadIdx.x & 63, ty = threadIdx.x >> 6;
  for (int r = ty; r < 64; r += 4) {
    int k = k0 + r;
    tile[r][tx] = (k < K) ? W[((long long)e * K + k) * N + n0 + tx] : 0.f;
  }
  __syncthreads();
  for (int r = ty; r < 64; r += 4) {
    int n = n0 + r;
    Wp[((long long)e * N + n) * KP + k0 + tx] = __float2bfloat16(tile[tx][r]);
  }
}

// ---------------- BN param folding ----------------
__global__ void k_prep_small(const float* b0, const float* g0, const float* be0,
                             const float* m0, const float* v0,
                             const float* b1, const float* g1, const float* be1,
                             const float* m1, const float* v1,
                             const float* bt1, const float* tg, const float* tb,
                             const float* tm, const float* tv,
                             float* scale0, float* ebias0, float* scale1, float* ebias1,
                             float* tscale, float* tbias) {
  int i = blockIdx.x * 256 + threadIdx.x;
  if (i < H0_) scale0[i] = g0[i] * rsqrtf(v0[i] + 1e-5f);
  if (i < H1_) scale1[i] = g1[i] * rsqrtf(v1[i] + 1e-5f);
  if (i < T_ * TH_) {
    float s = tg[i] * rsqrtf(tv[i] + 1e-5f);
    tscale[i] = s;
    tbias[i] = (bt1[i] - tm[i]) * s + tb[i];
  }
  if (i < E_ * H0_) {
    int n = i & (H0_ - 1);
    float s = g0[n] * rsqrtf(v0[n] + 1e-5f);
    ebias0[i] = (b0[i] - m0[n]) * s + be0[n];
  }
  if (i < E_ * H1_) {
    int n = i & (H1_ - 1);
    float s = g1[n] * rsqrtf(v1[n] + 1e-5f);
    ebias1[i] = (b1[i] - m1[n]) * s + be1[n];
  }
}

// ---------------- gate logits + softmax over 8 experts ----------------
__global__ __launch_bounds__(256) void k_gates(const __hip_bfloat16* __restrict__ x,
                                               const float* __restrict__ Wg,
                                               const float* __restrict__ bg,
                                               float* __restrict__ gates) {
  int gidx = blockIdx.x * 256 + threadIdx.x;
  int b = gidx >> 4, te = gidx & 15;
  int t = te >> 3, e = te & 7;
  const __hip_bfloat16* xr = x + (long long)b * K0P;
  const float* wg = Wg + ((long long)t * D0_) * E_ + e;
  float acc = bg[t * E_ + e];
  int k = 0;
  for (; k + 8 <= D0_; k += 8) {
    bf16x8 xv = *reinterpret_cast<const bf16x8*>(xr + k);
#pragma unroll
    for (int j = 0; j < 8; ++j)
      acc += (float)xv[j] * wg[(long long)(k + j) * E_];
  }
  for (; k < D0_; ++k) acc += __bfloat162float(xr[k]) * wg[(long long)k * E_];
  float mx = acc;
#pragma unroll
  for (int o = 1; o < 8; o <<= 1) mx = fmaxf(mx, __shfl_xor(mx, o));
  float p = __expf(acc - mx);
  float s = p;
#pragma unroll
  for (int o = 1; o < 8; o <<= 1) s += __shfl_xor(s, o);
  gates[((long long)t * B_ + b) * E_ + e] = p / s;
}

// ---------------- grouped GEMM + BN + ReLU -> bf16, 8-phase schedule ----------------
// 256x256 tile, BK=64, 8 waves; even K-tile count (no tail).
// Epilogue: acc -> LDS (chunk-swizzled) -> coalesced dwordx4 C stores.
__global__ __launch_bounds__(512, 1) void k_gemm(
    const __hip_bfloat16* __restrict__ Aall, long long strideAe, int lda,
    const __hip_bfloat16* __restrict__ Ball, long long strideBe, int ldb,
    __hip_bfloat16* __restrict__ Call, long long strideCe, int N,
    const float* __restrict__ scale, const float* __restrict__ ebias, int strideEb,
    int K) {
  __shared__ __align__(16) char SMEM[131072];
  char (*As)[2][16384] = reinterpret_cast<char (*)[2][16384]>(SMEM);           // [slot][half]
  char (*Bs)[2][16384] = reinterpret_cast<char (*)[2][16384]>(SMEM + 65536);

  const int e = blockIdx.z;
  const char* A = reinterpret_cast<const char*>(Aall + (long long)e * strideAe +
                                                (long long)blockIdx.x * 256 * lda);
  const char* Bw = reinterpret_cast<const char*>(Ball + (long long)e * strideBe +
                                                 (long long)blockIdx.y * 256 * ldb);
  const int ldab = lda * 2, ldbb = ldb * 2;

  const int tid = threadIdx.x;
  const int lane = tid & 63;
  const int wid = tid >> 6;
  const int wq_r = wid >> 2, wq_c = wid & 3;  // within-quadrant: 2Mx4N waves

  const int srow = tid >> 3;                          // 0..63
  const int swz = ((tid & 7) << 4) ^ ((srow & 7) << 4);

  auto STG_A = [&](int kt, int half, int slot) {
#pragma unroll
    for (int j = 0; j < 2; ++j) {
      const int lrow = srow + j * 64;
      load_lds16f(A + (long long)(half * 128 + lrow) * ldab + kt * 128 + swz,
                  &As[slot][half][j * 8192 + tid * 16]);
    }
  };
  auto STG_B = [&](int kt, int half, int slot) {
#pragma unroll
    for (int j = 0; j < 2; ++j) {
      const int lrow = srow + j * 64;
      load_lds16f(Bw + (long long)(half * 128 + lrow) * ldbb + kt * 128 + swz,
                  &Bs[slot][half][j * 8192 + tid * 16]);
    }
  };

  bf16x8 af[2][4], bq[2][2];
  auto LDA = [&](int slot, int half) {
#pragma unroll
    for (int kk = 0; kk < 2; ++kk) {
      const int kb = kk * 64 + (lane >> 4) * 16;
#pragma unroll
      for (int m = 0; m < 4; ++m) {
        const int lrow = wq_r * 64 + m * 16 + (lane & 15);
        af[kk][m] = *reinterpret_cast<const bf16x8*>(
            &As[slot][half][lrow * 128 + (kb ^ ((lane & 7) << 4))]);
      }
    }
  };
  auto LDB = [&](int slot, int half) {
#pragma unroll
    for (int kk = 0; kk < 2; ++kk) {
      const int kb = kk * 64 + (lane >> 4) * 16;
#pragma unroll
      for (int n = 0; n < 2; ++n) {
        const int lrow = wq_c * 32 + n * 16 + (lane & 15);
        bq[kk][n] = *reinterpret_cast<const bf16x8*>(
            &Bs[slot][half][lrow * 128 + (kb ^ ((lane & 7) << 4))]);
      }
    }
  };

  f32x4 acc[2][2][4][2];
#pragma unroll
  for (int a = 0; a < 2; ++a)
#pragma unroll
    for (int b = 0; b < 2; ++b)
#pragma unroll
      for (int m = 0; m < 4; ++m)
#pragma unroll
        for (int n = 0; n < 2; ++n) acc[a][b][m][n] = (f32x4){0.f, 0.f, 0.f, 0.f};

#define MMQ(QM, QN)                                                            \
  do {                                                                         \
    __builtin_amdgcn_s_setprio(1);                                             \
    _Pragma("unroll") for (int kk = 0; kk < 2; ++kk)                           \
        _Pragma("unroll") for (int m = 0; m < 4; ++m)                          \
            _Pragma("unroll") for (int n = 0; n < 2; ++n)                      \
                acc[QM][QN][m][n] = __builtin_amdgcn_mfma_f32_16x16x32_bf16(   \
                    af[kk][m], bq[kk][n], acc[QM][QN][m][n], 0, 0, 0);         \
    __builtin_amdgcn_s_setprio(0);                                             \
  } while (0)

  const int nk = K / 64;
  const int nj = nk >> 1;  // K chosen so nk is even (no tail)

  // prologue: t0 full, then t1.A0, t1.B1 -> vmcnt(4): t0 landed
  STG_A(0, 0, 0); STG_A(0, 1, 0); STG_B(0, 0, 0); STG_B(0, 1, 0);
  if (nk > 1) { STG_A(1, 0, 1); STG_B(1, 1, 1); }
  asm volatile("s_waitcnt vmcnt(4)" ::: "memory");
  BARX;

  for (int j = 0; j < nj; ++j) {
    const int t1 = 2 * j + 1, t2 = 2 * j + 2, t3 = 2 * j + 3;
    const bool more = (t2 < nk);
    // ---- tile t0 = 2j (slot 0) ----
    LDA(0, 0); LDB(0, 0);
    STG_A(t1, 1, 1);
    BARX; LGKM0; MMQ(0, 0); BARX;
    LDB(0, 1);
    STG_B(t1, 0, 1);
    BARX; LGKM0; MMQ(0, 1); BARX;
    LDA(0, 1);
    if (more) STG_A(t2, 0, 0);
    BARX; LGKM0; MMQ(1, 1); BARX;
    LDB(0, 0);
    if (more) STG_B(t2, 1, 0);
    BARX; LGKM0; MMQ(1, 0);
    if (more) { asm volatile("s_waitcnt vmcnt(4)" ::: "memory"); }
    else      { asm volatile("s_waitcnt vmcnt(0)" ::: "memory"); }
    BARX;
    // ---- tile t1 (slot 1) ----
    LDA(1, 0); LDB(1, 0);
    if (more) STG_A(t2, 1, 0);
    BARX; LGKM0; MMQ(0, 0); BARX;
    LDB(1, 1);
    if (more) STG_B(t2, 0, 0);
    BARX; LGKM0; MMQ(0, 1); BARX;
    LDA(1, 1);
    if (more) STG_A(t3, 0, 1);
    BARX; LGKM0; MMQ(1, 1); BARX;
    LDB(1, 0);
    if (more) STG_B(t3, 1, 1);
    BARX; LGKM0; MMQ(1, 0);
    if (more) { asm volatile("s_waitcnt vmcnt(4)" ::: "memory"); }
    BARX;
  }
#undef MMQ

  // ---- epilogue: acc -> LDS (chunk-swizzled) -> coalesced dwordx4 stores ----
  __syncthreads();  // all MFMA LDS reads done -> safe to overwrite SMEM
  __hip_bfloat16* C = Call + (long long)e * strideCe;
  const float* eb = ebias + e * strideEb;
  const int m0 = blockIdx.x * 256, n0 = blockIdx.y * 256;
#pragma unroll
  for (int Qm = 0; Qm < 2; ++Qm)
#pragma unroll
    for (int Qn = 0; Qn < 2; ++Qn)
#pragma unroll
      for (int n = 0; n < 2; ++n) {
        const int col = Qn * 128 + wq_c * 32 + n * 16 + (lane & 15);
        const float s = scale[n0 + col];
        const float bb = eb[n0 + col];
#pragma unroll
        for (int m = 0; m < 4; ++m) {
#pragma unroll
          for (int i = 0; i < 4; ++i) {
            const int row = Qm * 128 + wq_r * 64 + m * 16 + (lane >> 4) * 4 + i;
            const float v = fmaxf(acc[Qm][Qn][m][n][i] * s + bb, 0.f);
            const int byt = row * 512 + ((((col >> 3) ^ (row & 7)) << 4) | ((col & 7) << 1));
            *reinterpret_cast<__hip_bfloat16*>(SMEM + byt) = __float2bfloat16(v);
          }
        }
      }
  __syncthreads();
#pragma unroll
  for (int it = 0; it < 16; ++it) {
    const int row = it * 16 + (tid >> 5);
    const int c16 = tid & 31;
    const f32x4 d = *reinterpret_cast<const f32x4*>(
        SMEM + row * 512 + ((c16 ^ (row & 7)) << 4));
    *reinterpret_cast<f32x4*>(
        reinterpret_cast<char*>(C + (long long)(m0 + row) * N + n0) + c16 * 16) = d;
  }
}

// ---------------- gate-weighted combine: fea[t][b][:] = sum_e g[t][b][e]*h1[e][b][:] ----------------
__global__ __launch_bounds__(256) void k_combine(const __hip_bfloat16* __restrict__ h1,
                                                 const float* __restrict__ gates,
                                                 __hip_bfloat16* __restrict__ fea) {
  const int idx = blockIdx.x * 256 + threadIdx.x;  // 0 .. B*H1/8-1
  const int b = idx >> 5, c = idx & 31;
  const f32x4* gp0 = reinterpret_cast<const f32x4*>(gates + (long long)b * E_);
  const f32x4* gp1 = reinterpret_cast<const f32x4*>(gates + ((long long)B_ + b) * E_);
  const f32x4 g0lo = gp0[0], g0hi = gp0[1];
  const f32x4 g1lo = gp1[0], g1hi = gp1[1];

  float a0[8], a1[8];
#pragma unroll
  for (int j = 0; j < 8; ++j) { a0[j] = 0.f; a1[j] = 0.f; }

#pragma unroll
  for (int ee = 0; ee < 8; ++ee) {
    bf16x8 hv = *reinterpret_cast<const bf16x8*>(
        h1 + ((long long)ee * B_ + b) * H1_ + c * 8);
    const float ga = (ee < 4) ? g0lo[ee & 3] : g0hi[ee & 3];
    const float gb = (ee < 4) ? g1lo[ee & 3] : g1hi[ee & 3];
#pragma unroll
    for (int j = 0; j < 8; ++j) {
      float v = (float)hv[j];
      a0[j] += ga * v;
      a1[j] += gb * v;
    }
  }
  bf16x8 o0, o1;
#pragma unroll
  for (int j = 0; j < 8; ++j) { o0[j] = (__bf16)a0[j]; o1[j] = (__bf16)a1[j]; }
  *reinterpret_cast<bf16x8*>(fea + (long long)b * H1_ + c * 8) = o0;
  *reinterpret_cast<bf16x8*>(fea + ((long long)B_ + b) * H1_ + c * 8) = o1;
}

// ---------------- per-task tower MLP + sigmoid ----------------
__global__ __launch_bounds__(256) void k_tower2(
    const __hip_bfloat16* __restrict__ fea, const float* __restrict__ Wt1,
    const float* __restrict__ Wt2, const float* __restrict__ bt2,
    const float* __restrict__ tscale, const float* __restrict__ tbias,
    float* __restrict__ out) {
  __shared__ __align__(16) char Ws[TH_ * 512];  // Ws[h][k] bf16, swizzled
  const int t = blockIdx.y;
  const int tid = threadIdx.x;
  const int lane = tid & 63, wv = tid >> 6;

  const int row = blockIdx.x * 64 + wv * 16 + (lane & 15);
  const int g4 = lane >> 4;

  for (int it = 0; it < 16; ++it) {
    int idx = it * 256 + tid;
    int h = idx & 127, kc = idx >> 7;
    bf16x8 v;
#pragma unroll
    for (int j = 0; j < 8; ++j)
      v[j] = (__bf16)Wt1[((long long)t * H1_ + kc * 8 + j) * TH_ + h];
    int byt = h * 512 + ((kc * 16) ^ ((h & 7) << 4));
    *reinterpret_cast<bf16x8*>(Ws + byt) = v;
  }

  bf16x8 af[8];
  {
    const __hip_bfloat16* fp = fea + ((long long)t * B_ + row) * H1_ + g4 * 8;
#pragma unroll
    for (int c = 0; c < 8; ++c)
      af[c] = *reinterpret_cast<const bf16x8*>(fp + c * 32);
  }
  __syncthreads();

  f32x4 acc[8];
#pragma unroll
  for (int n = 0; n < 8; ++n) acc[n] = (f32x4){0.f, 0.f, 0.f, 0.f};
#pragma unroll
  for (int c = 0; c < 8; ++c) {
    int kb = c * 64 + g4 * 16;
#pragma unroll
    for (int n = 0; n < 8; ++n) {
      int hrow = n * 16 + (lane & 15);
      bf16x8 bv = *reinterpret_cast<const bf16x8*>(Ws + hrow * 512 + (kb ^ ((hrow & 7) << 4)));
      acc[n] = __builtin_amdgcn_mfma_f32_16x16x32_bf16(af[c], bv, acc[n], 0, 0, 0);
    }
  }

  float part[4] = {0.f, 0.f, 0.f, 0.f};
#pragma unroll
  for (int n = 0; n < 8; ++n) {
    int col = n * 16 + (lane & 15);
    float s = tscale[t * TH_ + col], bb = tbias[t * TH_ + col], w2 = Wt2[t * TH_ + col];
#pragma unroll
    for (int i = 0; i < 4; ++i)
      part[i] += fmaxf(acc[n][i] * s + bb, 0.f) * w2;
  }
#pragma unroll
  for (int o = 1; o < 16; o <<= 1) {
#pragma unroll
    for (int i = 0; i < 4; ++i) part[i] += __shfl_xor(part[i], o);
  }
  if ((lane & 15) == 0) {
    int rbase = blockIdx.x * 64 + wv * 16 + g4 * 4;
    float b2 = bt2[t];
#pragma unroll
    for (int i = 0; i < 4; ++i) {
      float z = part[i] + b2;
      out[(long long)t * B_ + rbase + i] = 1.f / (1.f + __expf(-z));
    }
  }
}

extern "C" void kernel_launch(void* const* d_in, const int* in_sizes, int n_in,
                              void* d_out, int out_size, void* d_ws, size_t ws_size,
                              hipStream_t stream) {
  const int*   cat = (const int*)d_in[0];
  const float* num = (const float*)d_in[1];
  const float* emb = (const float*)d_in[3];
  const float* W0  = (const float*)d_in[4];
  const float* b0  = (const float*)d_in[5];
  const float* g0  = (const float*)d_in[6];
  const float* be0 = (const float*)d_in[7];
  const float* m0  = (const float*)d_in[8];
  const float* v0  = (const float*)d_in[9];
  const float* W1  = (const float*)d_in[10];
  const float* b1  = (const float*)d_in[11];
  const float* g1  = (const float*)d_in[12];
  const float* be1 = (const float*)d_in[13];
  const float* m1  = (const float*)d_in[14];
  const float* v1  = (const float*)d_in[15];
  const float* Wg  = (const float*)d_in[16];
  const float* bg  = (const float*)d_in[17];
  const float* Wt1 = (const float*)d_in[18];
  const float* bt1 = (const float*)d_in[19];
  const float* tg  = (const float*)d_in[20];
  const float* tb  = (const float*)d_in[21];
  const float* tm  = (const float*)d_in[22];
  const float* tv  = (const float*)d_in[23];
  const float* Wt2 = (const float*)d_in[24];
  const float* bt2 = (const float*)d_in[25];
  float* out = (float*)d_out;

  char* ws = (char*)d_ws;
  if (ws_size < 247496704ULL) return;

  __hip_bfloat16* x_bf = (__hip_bfloat16*)(ws + 0ULL);            // 16384*640*2
  __hip_bfloat16* W0p  = (__hip_bfloat16*)(ws + 20971520ULL);     // 8*512*640*2
  __hip_bfloat16* W1p  = (__hip_bfloat16*)(ws + 26214400ULL);     // 8*256*512*2
  float* gates   = (float*)(ws + 28311552ULL);                    // 2*16384*8*4
  float* scale0  = (float*)(ws + 29360128ULL);
  float* ebias0  = (float*)(ws + 29362176ULL);
  float* scale1  = (float*)(ws + 29378560ULL);
  float* ebias1  = (float*)(ws + 29379584ULL);
  float* tscale  = (float*)(ws + 29387776ULL);
  float* tbias   = (float*)(ws + 29388800ULL);
  __hip_bfloat16* h0  = (__hip_bfloat16*)(ws + 29392896ULL);      // 8*16384*512*2
  __hip_bfloat16* h1  = (__hip_bfloat16*)(ws + 163610624ULL);     // 8*16384*256*2
  __hip_bfloat16* fea = (__hip_bfloat16*)(ws + 230719488ULL);     // 2*16384*256*2

  // weight prep + BN folding
  k_wprep<<<dim3(K0P / 64, H0_ / 64, E_), 256, 0, stream>>>(W0, W0p, D0_, H0_, K0P);
  k_wprep<<<dim3(H0_ / 64, H1_ / 64, E_), 256, 0, stream>>>(W1, W1p, H0_, H1_, H0_);
  k_prep_small<<<16, 256, 0, stream>>>(b0, g0, be0, m0, v0, b1, g1, be1, m1, v1,
                                       bt1, tg, tb, tm, tv,
                                       scale0, ebias0, scale1, ebias1, tscale, tbias);
  // embedding + concat
  k_embed<<<B_, 256, 0, stream>>>(cat, num, emb, x_bf);
  // gates
  k_gates<<<B_ * 16 / 256, 256, 0, stream>>>(x_bf, Wg, bg, gates);
  // layer 0: [B,640] x [E,512,640]^T -> h0 [E,B,512]  (nk=10, even)
  k_gemm<<<dim3(B_ / 256, H0_ / 256, E_), 512, 0, stream>>>(
      x_bf, 0LL, K0P, W0p, (long long)H0_ * K0P, K0P,
      h0, (long long)B_ * H0_, H0_, scale0, ebias0, H0_, K0P);
  // layer 1: h0 [E,B,512] x [E,256,512]^T -> h1 [E,B,256]  (nk=8, even)
  k_gemm<<<dim3(B_ / 256, H1_ / 256, E_), 512, 0, stream>>>(
      h0, (long long)B_ * H0_, H0_, W1p, (long long)H1_ * H0_, H0_,
      h1, (long long)B_ * H1_, H1_, scale1, ebias1, H1_, H0_);
  // gate-weighted combine (both tasks, one h1 pass)
  k_combine<<<B_ * H1_ / 8 / 256, 256, 0, stream>>>(h1, gates, fea);
  // per-task tower MLP + sigmoid
  k_tower2<<<dim3(B_ / 64, T_), 256, 0, stream>>>(fea, Wt1, Wt2, bt2,
                                                  tscale, tbias, out);
}